// Round 1
// baseline (9828.835 us; speedup 1.0000x reference)
//
#include <hip/hip_runtime.h>
#include <math.h>

#define NN 20000
#define EE 320000
#define BN_SC 0.9999950000374997f

// ======================= CSR build (by destination col) =======================
__global__ __launch_bounds__(256) void k_count(const int* __restrict__ colv, int* __restrict__ cnt) {
  int e = blockIdx.x * 256 + threadIdx.x;
  if (e < EE) atomicAdd(&cnt[colv[e]], 1);
}

__global__ __launch_bounds__(1024) void k_scan(const int* __restrict__ cnt, int* __restrict__ offs) {
  __shared__ int sb[1024];
  __shared__ int sc;
  int t = threadIdx.x;
  if (t == 0) { sc = 0; offs[0] = 0; }
  __syncthreads();
  for (int base = 0; base < NN; base += 1024) {
    int v = (base + t < NN) ? cnt[base + t] : 0;
    sb[t] = v;
    __syncthreads();
    for (int off = 1; off < 1024; off <<= 1) {
      int x = (t >= off) ? sb[t - off] : 0;
      __syncthreads();
      sb[t] += x;
      __syncthreads();
    }
    if (base + t < NN) offs[base + t + 1] = sc + sb[t];
    __syncthreads();
    if (t == 0) sc += sb[1023];
    __syncthreads();
  }
}

__global__ __launch_bounds__(256) void k_fill(const int* __restrict__ colv, const int* __restrict__ offs,
                                              int* __restrict__ cur, int* __restrict__ eid) {
  int e = blockIdx.x * 256 + threadIdx.x;
  if (e < EE) {
    int d = colv[e];
    int p = atomicAdd(&cur[d], 1);
    eid[offs[d] + p] = e;
  }
}

// deterministic per-node edge order (stable summation across replays)
__global__ __launch_bounds__(256) void k_sort(const int* __restrict__ offs, int* __restrict__ eid) {
  int n = blockIdx.x * 256 + threadIdx.x;
  if (n >= NN) return;
  int j0 = offs[n], j1 = offs[n + 1];
  for (int i = j0 + 1; i < j1; ++i) {
    int v = eid[i];
    int j = i - 1;
    while (j >= j0 && eid[j] > v) { eid[j + 1] = eid[j]; --j; }
    eid[j + 1] = v;
  }
}

// ======================= fused edge MLP + cosine =======================
// 8 edges (16 rows: rows 0..7 = first halves, 8..15 = second halves) per block of 256.
// LDS: H1[16][512] (32K) + Wt[64][64] k-major (16K) + H2[16][256] (16K) = 64KB.
__device__ __forceinline__ void stage_w64(const float* __restrict__ Wsrc, int crow0, int ldk, int k0,
                                          float* __restrict__ Wts, int tid) {
  int c = tid >> 2;
  int kq = (tid & 3) * 16;
  const float* src = Wsrc + (size_t)(crow0 + c) * ldk + k0 + kq;
#pragma unroll
  for (int u = 0; u < 4; ++u) {
    float4 v = *(const float4*)(src + 4 * u);
    float* dst = Wts + (size_t)(kq + 4 * u) * 64 + c;
    dst[0] = v.x;
    dst[64] = v.y;
    dst[128] = v.z;
    dst[192] = v.w;
  }
}

__device__ __forceinline__ void tile_step8(const float* xr0, const float* xr1,
                                           const float* __restrict__ Wts, int cg, int k8,
                                           float& a00, float& a01, float& a10, float& a11) {
  float4 A0 = *(const float4*)(xr0 + k8);
  float4 A1 = *(const float4*)(xr0 + k8 + 4);
  float4 B0 = *(const float4*)(xr1 + k8);
  float4 B1 = *(const float4*)(xr1 + k8 + 4);
  const float* wp = Wts + (size_t)k8 * 64 + 2 * cg;
  float2 w;
  w = *(const float2*)(wp);       a00 += A0.x*w.x; a01 += A0.x*w.y; a10 += B0.x*w.x; a11 += B0.x*w.y;
  w = *(const float2*)(wp + 64);  a00 += A0.y*w.x; a01 += A0.y*w.y; a10 += B0.y*w.x; a11 += B0.y*w.y;
  w = *(const float2*)(wp + 128); a00 += A0.z*w.x; a01 += A0.z*w.y; a10 += B0.z*w.x; a11 += B0.z*w.y;
  w = *(const float2*)(wp + 192); a00 += A0.w*w.x; a01 += A0.w*w.y; a10 += B0.w*w.x; a11 += B0.w*w.y;
  w = *(const float2*)(wp + 256); a00 += A1.x*w.x; a01 += A1.x*w.y; a10 += B1.x*w.x; a11 += B1.x*w.y;
  w = *(const float2*)(wp + 320); a00 += A1.y*w.x; a01 += A1.y*w.y; a10 += B1.y*w.x; a11 += B1.y*w.y;
  w = *(const float2*)(wp + 384); a00 += A1.z*w.x; a01 += A1.z*w.y; a10 += B1.z*w.x; a11 += B1.z*w.y;
  w = *(const float2*)(wp + 448); a00 += A1.w*w.x; a01 += A1.w*w.y; a10 += B1.w*w.x; a11 += B1.w*w.y;
}

__global__ __launch_bounds__(256) void k_edge_mlp(
    const float* __restrict__ X,
    const float* __restrict__ W1, const float* __restrict__ b1,
    const float* __restrict__ W2, const float* __restrict__ b2,
    const float* __restrict__ W3, const float* __restrict__ b3,
    float* __restrict__ ew) {
  __shared__ float H1s[16 * 512];
  __shared__ float Wts[64 * 64];
  __shared__ float H2s[16 * 256];
  const int tid = threadIdx.x;
  const int e0 = blockIdx.x * 8;
  const int rg = tid >> 5;   // 0..7 -> rows 2rg, 2rg+1
  const int cg = tid & 31;   // cols 2cg, 2cg+1 within a 64-col chunk
  const int r0 = rg * 2, r1 = r0 + 1;
  const float* xr0 = X + (size_t)(e0 + (r0 & 7)) * 128 + (r0 >> 3) * 64;
  const float* xr1 = X + (size_t)(e0 + (r1 & 7)) * 128 + (r1 >> 3) * 64;

  // ---- Layer 1: K=64, 512 cols ----
  for (int cp = 0; cp < 8; ++cp) {
    stage_w64(W1, cp * 64, 64, 0, Wts, tid);
    __syncthreads();
    int c0 = cp * 64 + 2 * cg;
    float a00 = b1[c0], a01 = b1[c0 + 1];
    float a10 = a00, a11 = a01;
#pragma unroll
    for (int k8 = 0; k8 < 64; k8 += 8)
      tile_step8(xr0, xr1, Wts, cg, k8, a00, a01, a10, a11);
    *(float2*)&H1s[r0 * 512 + c0] = make_float2(fmaxf(a00, 0.f) * BN_SC, fmaxf(a01, 0.f) * BN_SC);
    *(float2*)&H1s[r1 * 512 + c0] = make_float2(fmaxf(a10, 0.f) * BN_SC, fmaxf(a11, 0.f) * BN_SC);
    __syncthreads();
  }
  // ---- Layer 2: K=512, 256 cols ----
  for (int cp = 0; cp < 4; ++cp) {
    int c0 = cp * 64 + 2 * cg;
    float a00 = b2[c0], a01 = b2[c0 + 1], a10 = a00, a11 = a01;
    for (int kt = 0; kt < 8; ++kt) {
      stage_w64(W2, cp * 64, 512, kt * 64, Wts, tid);
      __syncthreads();
      const float* h1a = &H1s[r0 * 512 + kt * 64];
      const float* h1b = &H1s[r1 * 512 + kt * 64];
#pragma unroll
      for (int k8 = 0; k8 < 64; k8 += 8)
        tile_step8(h1a, h1b, Wts, cg, k8, a00, a01, a10, a11);
      __syncthreads();
    }
    *(float2*)&H2s[r0 * 256 + c0] = make_float2(fmaxf(a00, 0.f) * BN_SC, fmaxf(a01, 0.f) * BN_SC);
    *(float2*)&H2s[r1 * 256 + c0] = make_float2(fmaxf(a10, 0.f) * BN_SC, fmaxf(a11, 0.f) * BN_SC);
  }
  __syncthreads();
  // ---- Layer 3: K=256, 128 cols, linear; H3 aliases H1 (dead) ----
  float* H3s = H1s;
  for (int cp = 0; cp < 2; ++cp) {
    int c0 = cp * 64 + 2 * cg;
    float a00 = b3[c0], a01 = b3[c0 + 1], a10 = a00, a11 = a01;
    for (int kt = 0; kt < 4; ++kt) {
      stage_w64(W3, cp * 64, 256, kt * 64, Wts, tid);
      __syncthreads();
      const float* h2a = &H2s[r0 * 256 + kt * 64];
      const float* h2b = &H2s[r1 * 256 + kt * 64];
#pragma unroll
      for (int k8 = 0; k8 < 64; k8 += 8)
        tile_step8(h2a, h2b, Wts, cg, k8, a00, a01, a10, a11);
      __syncthreads();
    }
    *(float2*)&H3s[r0 * 128 + c0] = make_float2(a00, a01);
    *(float2*)&H3s[r1 * 128 + c0] = make_float2(a10, a11);
  }
  __syncthreads();
  // ---- cosine head: 32 threads per edge ----
  {
    int i = tid >> 5;
    int j = tid & 31;
    float dot = 0.f, s1 = 0.f, s2 = 0.f;
#pragma unroll
    for (int f = j; f < 128; f += 32) {
      float a = H3s[i * 128 + f];
      float b = H3s[(8 + i) * 128 + f];
      dot += a * b;
      s1 += a * a;
      s2 += b * b;
    }
#pragma unroll
    for (int m = 16; m >= 1; m >>= 1) {
      dot += __shfl_xor(dot, m, 32);
      s1 += __shfl_xor(s1, m, 32);
      s2 += __shfl_xor(s2, m, 32);
    }
    if (j == 0) {
      float n1 = fmaxf(sqrtf(s1), 1e-8f);
      float n2 = fmaxf(sqrtf(s2), 1e-8f);
      float cosv = dot / (n1 * n2);
      ew[e0 + i] = (cosv + 1.f) * 0.5f;
    }
  }
}

// ======================= Laplacian weights =======================
__global__ __launch_bounds__(256) void k_deg(const int* __restrict__ rowi, const int* __restrict__ colv,
                                             const float* __restrict__ ew, float* __restrict__ deg) {
  int e = blockIdx.x * 256 + threadIdx.x;
  if (e < EE) {
    int r = rowi[e];
    float w = (r == colv[e]) ? 0.f : ew[e];
    atomicAdd(&deg[r], w);
  }
}
__global__ __launch_bounds__(256) void k_dinv(const float* __restrict__ deg, float* __restrict__ dinv) {
  int n = blockIdx.x * 256 + threadIdx.x;
  if (n < NN) { float d = deg[n]; dinv[n] = d > 0.f ? 1.f / sqrtf(d) : 0.f; }
}
__global__ __launch_bounds__(256) void k_lapw(const int* __restrict__ rowi, const int* __restrict__ colv,
                                              const float* __restrict__ ew, const float* __restrict__ dinv,
                                              float* __restrict__ lapw) {
  int e = blockIdx.x * 256 + threadIdx.x;
  if (e < EE) {
    int r = rowi[e], c = colv[e];
    float w = (r == c) ? 0.f : ew[e];
    lapw[e] = -dinv[r] * w * dinv[c];
  }
}

// ======================= Cheb propagation: out = alpha*(L@x) + beta*y =======================
template <int DIM>
__global__ __launch_bounds__(256) void k_prop(const float* __restrict__ x, int ldx,
                                              const float* __restrict__ y, int ldy,
                                              float alpha, float beta,
                                              float* __restrict__ outv, int ldo,
                                              const float* __restrict__ lapw,
                                              const int* __restrict__ rowi,
                                              const int* __restrict__ offs,
                                              const int* __restrict__ eid) {
  constexpr int NPB = 256 / DIM;
  int n = blockIdx.x * NPB + threadIdx.x / DIM;
  int f = threadIdx.x % DIM;
  if (n >= NN) return;
  float acc = 0.f;
  int j1 = offs[n + 1];
  for (int j = offs[n]; j < j1; ++j) {
    int e = eid[j];
    acc += lapw[e] * x[(size_t)rowi[e] * ldx + f];
  }
  float r = alpha * acc;
  if (beta != 0.f) r += beta * y[(size_t)n * ldy + f];
  outv[(size_t)n * ldo + f] = r;
}

// ======================= cheb combine: relu(sum_k txk @ Wk) -> jk slice =======================
template <int DK>
__global__ __launch_bounds__(512) void k_combine(const float* __restrict__ t0, int ld0,
                                                 const float* __restrict__ t1, int ld1,
                                                 const float* __restrict__ t2, int ld2,
                                                 const float* __restrict__ t3, int ld3,
                                                 const float* __restrict__ W,
                                                 float* __restrict__ outp) {
  int n = blockIdx.x * 8 + (threadIdx.x >> 6);
  int c = threadIdx.x & 63;
  if (n >= NN) return;
  const float* r0 = t0 + (size_t)n * ld0;
  const float* r1 = t1 + (size_t)n * ld1;
  const float* r2 = t2 + (size_t)n * ld2;
  const float* r3 = t3 + (size_t)n * ld3;
  const float* w0 = W;
  const float* w1 = W + DK * 64;
  const float* w2 = W + 2 * DK * 64;
  const float* w3 = W + 3 * DK * 64;
  float acc = 0.f;
#pragma unroll 4
  for (int d = 0; d < DK; ++d) {
    acc += r0[d] * w0[d * 64 + c];
    acc += r1[d] * w1[d * 64 + c];
    acc += r2[d] * w2[d * 64 + c];
    acc += r3[d] * w3[d * 64 + c];
  }
  outp[(size_t)n * 256 + c] = fmaxf(acc, 0.f);
}

// ======================= classifier head =======================
__global__ void k_tr256(const float* __restrict__ A, float* __restrict__ At) {
  int c = blockIdx.x, k = threadIdx.x;
  At[(size_t)k * 256 + c] = A[(size_t)c * 256 + k];
}

__global__ __launch_bounds__(256) void k_mlogit(const float* __restrict__ jk, const float* __restrict__ Wm1t,
                                                const float* __restrict__ bm1, const float* __restrict__ Wm2,
                                                const float* __restrict__ bm2, float* __restrict__ logit1) {
  __shared__ float jks[16 * 256];
  __shared__ float red[16 * 8];
  int tid = threadIdx.x, n0 = blockIdx.x * 16;
  {
    const float4* src = (const float4*)(jk + (size_t)n0 * 256);
    float4* dst = (float4*)jks;
#pragma unroll
    for (int u = 0; u < 4; ++u) dst[tid + 256 * u] = src[tid + 256 * u];
  }
  __syncthreads();
  int c = tid;
  float acc[16];
  float bb = bm1[c];
#pragma unroll
  for (int r = 0; r < 16; ++r) acc[r] = bb;
  for (int k = 0; k < 256; k += 4) {
    float w0 = Wm1t[(size_t)(k + 0) * 256 + c];
    float w1 = Wm1t[(size_t)(k + 1) * 256 + c];
    float w2 = Wm1t[(size_t)(k + 2) * 256 + c];
    float w3 = Wm1t[(size_t)(k + 3) * 256 + c];
#pragma unroll
    for (int r = 0; r < 16; ++r) {
      float4 jv = *(const float4*)&jks[r * 256 + k];
      acc[r] += jv.x * w0 + jv.y * w1 + jv.z * w2 + jv.w * w3;
    }
  }
  float w20 = Wm2[c], w21 = Wm2[256 + c];
  int wid = tid >> 6, lane = tid & 63;
#pragma unroll
  for (int r = 0; r < 16; ++r) {
    float mv = fmaxf(acc[r], 0.f) * BN_SC;
    float v0 = mv * w20, v1 = mv * w21;
#pragma unroll
    for (int m = 32; m >= 1; m >>= 1) {
      v0 += __shfl_xor(v0, m, 64);
      v1 += __shfl_xor(v1, m, 64);
    }
    if (lane == 0) { red[r * 8 + wid] = v0; red[r * 8 + 4 + wid] = v1; }
  }
  __syncthreads();
  if (tid < 32) {
    int r = tid >> 1, cls = tid & 1;
    float s = red[r * 8 + cls * 4] + red[r * 8 + cls * 4 + 1] + red[r * 8 + cls * 4 + 2] + red[r * 8 + cls * 4 + 3];
    logit1[(size_t)(n0 + r) * 2 + cls] = s + bm2[cls];
  }
}

// ======================= bys branch =======================
__global__ __launch_bounds__(256) void k_h0(const float* __restrict__ feat, const float* __restrict__ Wl,
                                            const float* __restrict__ bl, float* __restrict__ h0) {
  int idx = blockIdx.x * 256 + threadIdx.x;
  if (idx >= NN * 16) return;
  int n = idx >> 4, j = idx & 15;
  const float* fr = feat + (size_t)n * 128;
  const float* wr = Wl + (size_t)j * 128;
  float acc = bl[j];
#pragma unroll 8
  for (int d = 0; d < 128; d += 4) {
    float4 f = *(const float4*)(fr + d);
    float4 w = *(const float4*)(wr + d);
    acc += f.x * w.x + f.y * w.y + f.z * w.z + f.w * w.w;
  }
  h0[idx] = acc;
}

__global__ __launch_bounds__(256) void k_bys(const float* __restrict__ hprev, const float* __restrict__ nz,
                                             float* __restrict__ hout,
                                             const float* __restrict__ ew, const int* __restrict__ rowi,
                                             const int* __restrict__ offs, const int* __restrict__ eid) {
  int idx = blockIdx.x * 256 + threadIdx.x;
  int n = idx >> 4, f = idx & 15;
  if (n >= NN) return;
  float acc = 0.f;
  int j1 = offs[n + 1];
  for (int j = offs[n]; j < j1; ++j) {
    int e = eid[j];
    acc += ew[e] * hprev[(size_t)rowi[e] * 16 + f];
  }
  hout[idx] = nz[idx] + acc;
}

// ======================= final: logit2 + softmaxes + max =======================
__global__ __launch_bounds__(256) void k_final(const float* __restrict__ states, const float* __restrict__ Whl,
                                               const float* __restrict__ bhl, const float* __restrict__ logit1,
                                               float* __restrict__ outp) {
  int n = blockIdx.x * 4 + (threadIdx.x >> 6);
  int l = threadIdx.x & 63;
  if (n >= NN) return;
  const float* sf = states + (size_t)n * 400;  // row-major reshape of [25][N][16]
  float a0 = 0.f, a1 = 0.f;
  for (int t = l; t < 400; t += 64) {
    float v = sf[t];
    a0 += v * Whl[t];
    a1 += v * Whl[400 + t];
  }
#pragma unroll
  for (int m = 32; m >= 1; m >>= 1) {
    a0 += __shfl_xor(a0, m, 64);
    a1 += __shfl_xor(a1, m, 64);
  }
  if (l == 0) {
    float z0 = 1.f / (1.f + expf(-(a0 + bhl[0])));
    float z1 = 1.f / (1.f + expf(-(a1 + bhl[1])));
    float p20 = 1.f / (1.f + expf(z1 - z0));
    float p21 = 1.f - p20;
    float l10 = logit1[(size_t)n * 2], l11 = logit1[(size_t)n * 2 + 1];
    float p10 = 1.f / (1.f + expf(l11 - l10));
    float p11 = 1.f - p10;
    outp[(size_t)n * 2] = p10;
    outp[(size_t)n * 2 + 1] = p11;
    outp[2 * NN + (size_t)n * 2] = p20;
    outp[2 * NN + (size_t)n * 2 + 1] = p21;
    outp[4 * NN + (size_t)n * 2] = fmaxf(p10, p20);
    outp[4 * NN + (size_t)n * 2 + 1] = fmaxf(p11, p21);
  }
}

// ======================= host =======================
extern "C" void kernel_launch(void* const* d_in, const int* in_sizes, int n_in,
                              void* d_out, int out_size, void* d_ws, size_t ws_size,
                              hipStream_t stream) {
  const float* feat = (const float*)d_in[0];
  const int* ei = (const int*)d_in[1];
  const float* xen = (const float*)d_in[2];
  const float* We1 = (const float*)d_in[3];
  const float* be1 = (const float*)d_in[4];
  const float* We2 = (const float*)d_in[5];
  const float* be2 = (const float*)d_in[6];
  const float* We3 = (const float*)d_in[7];
  const float* be3 = (const float*)d_in[8];
  const float* cw[4] = {(const float*)d_in[9], (const float*)d_in[10], (const float*)d_in[11], (const float*)d_in[12]};
  const float* Wm1 = (const float*)d_in[13];
  const float* bm1 = (const float*)d_in[14];
  const float* Wm2 = (const float*)d_in[15];
  const float* bm2 = (const float*)d_in[16];
  const float* Wl = (const float*)d_in[17];
  const float* bl = (const float*)d_in[18];
  const float* Whl = (const float*)d_in[19];
  const float* bhl = (const float*)d_in[20];
  const float* noise = (const float*)d_in[21];
  float* outp = (float*)d_out;

  char* wp_ = (char*)d_ws;
  auto alloc = [&](size_t bytes) {
    char* p = wp_;
    wp_ += (bytes + 255) & ~(size_t)255;
    return p;
  };
  float* ew = (float*)alloc((size_t)EE * 4);
  float* lapw = (float*)alloc((size_t)EE * 4);
  float* deg = (float*)alloc((size_t)NN * 4);
  float* dinv = (float*)alloc((size_t)NN * 4);
  int* cnt = (int*)alloc((size_t)NN * 4);
  int* offs = (int*)alloc((size_t)(NN + 1) * 4);
  int* eid = (int*)alloc((size_t)EE * 4);
  float* tx1 = (float*)alloc((size_t)NN * 128 * 4);
  float* tx2 = (float*)alloc((size_t)NN * 128 * 4);
  float* tx3 = (float*)alloc((size_t)NN * 128 * 4);
  float* jk = (float*)alloc((size_t)NN * 256 * 4);
  float* logit1 = (float*)alloc((size_t)NN * 2 * 4);
  float* Wm1t = (float*)alloc((size_t)256 * 256 * 4);
  float* h0 = (float*)alloc((size_t)NN * 16 * 4);
  float* states = (float*)alloc((size_t)25 * NN * 16 * 4);

  const int* rowi = ei;
  const int* colv = ei + EE;

  hipMemsetAsync(cnt, 0, (size_t)NN * 4, stream);
  hipMemsetAsync(deg, 0, (size_t)NN * 4, stream);
  k_count<<<1250, 256, 0, stream>>>(colv, cnt);
  k_scan<<<1, 1024, 0, stream>>>(cnt, offs);
  hipMemsetAsync(cnt, 0, (size_t)NN * 4, stream);
  k_fill<<<1250, 256, 0, stream>>>(colv, offs, cnt, eid);
  k_sort<<<79, 256, 0, stream>>>(offs, eid);

  k_edge_mlp<<<40000, 256, 0, stream>>>(xen, We1, be1, We2, be2, We3, be3, ew);

  k_deg<<<1250, 256, 0, stream>>>(rowi, colv, ew, deg);
  k_dinv<<<79, 256, 0, stream>>>(deg, dinv);
  k_lapw<<<1250, 256, 0, stream>>>(rowi, colv, ew, dinv, lapw);
  k_tr256<<<256, 256, 0, stream>>>(Wm1, Wm1t);

  // cheb layer 0 (input dim 128)
  k_prop<128><<<10000, 256, 0, stream>>>(feat, 128, feat, 128, 1.f, 0.f, tx1, 128, lapw, rowi, offs, eid);
  k_prop<128><<<10000, 256, 0, stream>>>(tx1, 128, feat, 128, 2.f, -1.f, tx2, 128, lapw, rowi, offs, eid);
  k_prop<128><<<10000, 256, 0, stream>>>(tx2, 128, tx1, 128, 2.f, -1.f, tx3, 128, lapw, rowi, offs, eid);
  k_combine<128><<<2500, 512, 0, stream>>>(feat, 128, tx1, 128, tx2, 128, tx3, 128, cw[0], jk);
  // cheb layers 1..3 (input dim 64, read from jk slice)
  for (int l = 1; l < 4; ++l) {
    const float* xin = jk + (l - 1) * 64;
    k_prop<64><<<5000, 256, 0, stream>>>(xin, 256, xin, 256, 1.f, 0.f, tx1, 64, lapw, rowi, offs, eid);
    k_prop<64><<<5000, 256, 0, stream>>>(tx1, 64, xin, 256, 2.f, -1.f, tx2, 64, lapw, rowi, offs, eid);
    k_prop<64><<<5000, 256, 0, stream>>>(tx2, 64, tx1, 64, 2.f, -1.f, tx3, 64, lapw, rowi, offs, eid);
    k_combine<64><<<2500, 512, 0, stream>>>(xin, 256, tx1, 64, tx2, 64, tx3, 64, cw[l], jk + l * 64);
  }
  k_mlogit<<<1250, 256, 0, stream>>>(jk, Wm1t, bm1, Wm2, bm2, logit1);

  k_h0<<<1250, 256, 0, stream>>>(feat, Wl, bl, h0);
  const float* hprev = h0;
  for (int s = 0; s < 25; ++s) {
    float* hout = states + (size_t)s * NN * 16;
    k_bys<<<1250, 256, 0, stream>>>(hprev, noise + (size_t)s * NN * 16, hout, ew, rowi, offs, eid);
    hprev = hout;
  }
  k_final<<<5000, 256, 0, stream>>>(states, Whl, bhl, logit1, outp);
}

// Round 2
// 3725.791 us; speedup vs baseline: 2.6381x; 2.6381x over previous
//
#include <hip/hip_runtime.h>
#include <math.h>

#define NN 20000
#define EE 320000
#define BN_SC 0.9999950000374997f

typedef __attribute__((ext_vector_type(8))) short bf16x8;
typedef __attribute__((ext_vector_type(4))) float f32x4;

__device__ __forceinline__ unsigned short f2b(float x) {
  unsigned int u = __builtin_bit_cast(unsigned int, x);
  u += 0x7FFFu + ((u >> 16) & 1u);
  return (unsigned short)(u >> 16);
}
__device__ __forceinline__ void split2(float x, unsigned short& h, unsigned short& l) {
  h = f2b(x);
  float hf = __builtin_bit_cast(float, (unsigned int)h << 16);
  l = f2b(x - hf);
}

// ======================= weight split prep =======================
__global__ __launch_bounds__(256) void k_wsplit(const float* __restrict__ W, unsigned short* __restrict__ Wh,
                                                unsigned short* __restrict__ Wl, int n) {
  int i = blockIdx.x * 256 + threadIdx.x;
  if (i < n) split2(W[i], Wh[i], Wl[i]);
}

// ======================= CSR build (by destination col) =======================
__global__ __launch_bounds__(256) void k_count(const int* __restrict__ colv, int* __restrict__ cnt) {
  int e = blockIdx.x * 256 + threadIdx.x;
  if (e < EE) atomicAdd(&cnt[colv[e]], 1);
}

__global__ __launch_bounds__(1024) void k_scan(const int* __restrict__ cnt, int* __restrict__ offs) {
  __shared__ int sb[1024];
  __shared__ int sc;
  int t = threadIdx.x;
  if (t == 0) { sc = 0; offs[0] = 0; }
  __syncthreads();
  for (int base = 0; base < NN; base += 1024) {
    int v = (base + t < NN) ? cnt[base + t] : 0;
    sb[t] = v;
    __syncthreads();
    for (int off = 1; off < 1024; off <<= 1) {
      int x = (t >= off) ? sb[t - off] : 0;
      __syncthreads();
      sb[t] += x;
      __syncthreads();
    }
    if (base + t < NN) offs[base + t + 1] = sc + sb[t];
    __syncthreads();
    if (t == 0) sc += sb[1023];
    __syncthreads();
  }
}

__global__ __launch_bounds__(256) void k_fill(const int* __restrict__ colv, const int* __restrict__ offs,
                                              int* __restrict__ cur, int* __restrict__ eid) {
  int e = blockIdx.x * 256 + threadIdx.x;
  if (e < EE) {
    int d = colv[e];
    int p = atomicAdd(&cur[d], 1);
    eid[offs[d] + p] = e;
  }
}

__global__ __launch_bounds__(256) void k_sort(const int* __restrict__ offs, int* __restrict__ eid) {
  int n = blockIdx.x * 256 + threadIdx.x;
  if (n >= NN) return;
  int j0 = offs[n], j1 = offs[n + 1];
  for (int i = j0 + 1; i < j1; ++i) {
    int v = eid[i];
    int j = i - 1;
    while (j >= j0 && eid[j] > v) { eid[j + 1] = eid[j]; --j; }
    eid[j + 1] = v;
  }
}

// ======================= fused edge MLP (MFMA split-bf16) + cosine =======================
// 32 edges (64 rows, halves interleaved: row 2i/2i+1 = edge i first/second half) per block.
// 256 threads = 4 waves. K-chunked fusion: H1 produced in 64-col chunks, consumed
// immediately into layer-2 register accumulators; H2 likewise chunked into layer 3.
// LDS planes are [64 rows][64 cols] ushort, 16B-chunk XOR swizzled: chunk' = chunk ^ (row&7).
#define MFMA16(a, b, c) __builtin_amdgcn_mfma_f32_16x16x32_bf16(a, b, c, 0, 0, 0)

__global__ __launch_bounds__(256, 2) void k_edge_mlp(
    const float* __restrict__ X,
    const unsigned short* __restrict__ W1h, const unsigned short* __restrict__ W1l, const float* __restrict__ b1,
    const unsigned short* __restrict__ W2h, const unsigned short* __restrict__ W2l, const float* __restrict__ b2,
    const unsigned short* __restrict__ W3h, const unsigned short* __restrict__ W3l, const float* __restrict__ b3,
    float* __restrict__ ew) {
  // POOL (32KB): Xh|Xl|H1h|H1l during phases A/B, re-used as H3 (f32 [64][128]) in phase C tail.
  __shared__ __align__(16) unsigned short POOL[4 * 4096];
  __shared__ __align__(16) unsigned short H2h[4096], H2l[4096];
  unsigned short* Xh = POOL;
  unsigned short* Xl = POOL + 4096;
  unsigned short* H1h = POOL + 8192;
  unsigned short* H1l = POOL + 12288;
  float* H3 = (float*)POOL;  // 64*128 f32 = 32KB, aliases all four planes (dead by then)

  const int tid = threadIdx.x;
  const int wv = tid >> 6;
  const int lane = tid & 63;
  const int lr = lane & 15;   // MFMA row/col within 16
  const int lg = lane >> 4;   // k-group 0..3
  const int e0 = blockIdx.x * 32;

  // ---- stage X[64 rows][64 cols] as split bf16, swizzled ----
  {
    int row = tid >> 2, cq = tid & 3;
    const float* src = X + (size_t)(e0 + (row >> 1)) * 128 + (row & 1) * 64 + cq * 16;
#pragma unroll
    for (int half = 0; half < 2; ++half) {
      float4 a = ((const float4*)src)[2 * half];
      float4 b = ((const float4*)src)[2 * half + 1];
      float vals[8] = {a.x, a.y, a.z, a.w, b.x, b.y, b.z, b.w};
      unsigned short hs[8], ls[8];
#pragma unroll
      for (int j = 0; j < 8; ++j) split2(vals[j], hs[j], ls[j]);
      int chunk = (2 * cq + half) ^ (row & 7);
      int idx = row * 64 + chunk * 8;
#pragma unroll
      for (int j = 0; j < 8; ++j) { Xh[idx + j] = hs[j]; Xl[idx + j] = ls[j]; }
    }
  }
  __syncthreads();

  f32x4 acc2[4][4];  // layer-2 accum: wave owns cols 64wv..+63 (4 coltiles) x 4 rowtiles
#pragma unroll
  for (int rt = 0; rt < 4; ++rt)
#pragma unroll
    for (int ct = 0; ct < 4; ++ct) acc2[rt][ct] = f32x4{0.f, 0.f, 0.f, 0.f};

  // ===== phases A+B: 8 chunks of 64 H1-cols =====
  for (int kc = 0; kc < 8; ++kc) {
    // layer-1: wave wv owns rowtile wv, all 4 coltiles of this chunk. K=64.
    f32x4 acc1[4];
#pragma unroll
    for (int ct = 0; ct < 4; ++ct) acc1[ct] = f32x4{0.f, 0.f, 0.f, 0.f};
#pragma unroll
    for (int kt = 0; kt < 2; ++kt) {
      int arow = 16 * wv + lr;
      int aidx = arow * 64 + ((4 * kt + lg) ^ (arow & 7)) * 8;
      bf16x8 ah = *(const bf16x8*)&Xh[aidx];
      bf16x8 al = *(const bf16x8*)&Xl[aidx];
      int kk = 32 * kt + 8 * lg;
#pragma unroll
      for (int ct = 0; ct < 4; ++ct) {
        int col = 64 * kc + 16 * ct + lr;
        bf16x8 bh = *(const bf16x8*)(W1h + (size_t)col * 64 + kk);
        bf16x8 bl = *(const bf16x8*)(W1l + (size_t)col * 64 + kk);
        acc1[ct] = MFMA16(ah, bh, acc1[ct]);
        acc1[ct] = MFMA16(ah, bl, acc1[ct]);
        acc1[ct] = MFMA16(al, bh, acc1[ct]);
      }
    }
    __syncthreads();  // previous chunk's layer-2 reads of H1 are done
    // epilogue: bias + ReLU + BN, split to H1 planes (C/D layout: col=lr, row=4*lg+reg)
#pragma unroll
    for (int ct = 0; ct < 4; ++ct) {
      float bias = b1[64 * kc + 16 * ct + lr];
#pragma unroll
      for (int r = 0; r < 4; ++r) {
        float v = fmaxf(acc1[ct][r] + bias, 0.f) * BN_SC;
        unsigned short hs, ls;
        split2(v, hs, ls);
        int row = 16 * wv + 4 * lg + r;
        int colL = 16 * ct + lr;
        int idx = row * 64 + (((colL >> 3) ^ (row & 7)) * 8) + (colL & 7);
        H1h[idx] = hs;
        H1l[idx] = ls;
      }
    }
    __syncthreads();  // H1 chunk ready
    // layer-2 partial: wave owns cols 64wv..+63, all 64 rows. K=64 (this chunk).
#pragma unroll
    for (int kt = 0; kt < 2; ++kt) {
      bf16x8 ah[4], al[4];
#pragma unroll
      for (int rt = 0; rt < 4; ++rt) {
        int arow = 16 * rt + lr;
        int aidx = arow * 64 + ((4 * kt + lg) ^ (arow & 7)) * 8;
        ah[rt] = *(const bf16x8*)&H1h[aidx];
        al[rt] = *(const bf16x8*)&H1l[aidx];
      }
      int kg = 64 * kc + 32 * kt + 8 * lg;
#pragma unroll
      for (int ct = 0; ct < 4; ++ct) {
        int col = 64 * wv + 16 * ct + lr;
        bf16x8 bh = *(const bf16x8*)(W2h + (size_t)col * 512 + kg);
        bf16x8 bl = *(const bf16x8*)(W2l + (size_t)col * 512 + kg);
#pragma unroll
        for (int rt = 0; rt < 4; ++rt) {
          acc2[rt][ct] = MFMA16(ah[rt], bh, acc2[rt][ct]);
          acc2[rt][ct] = MFMA16(ah[rt], bl, acc2[rt][ct]);
          acc2[rt][ct] = MFMA16(al[rt], bh, acc2[rt][ct]);
        }
      }
    }
  }

  // ===== phase C: layer 3 via 4 H2 chunks of 64 cols =====
  f32x4 acc3[4][2];  // wave owns H3 cols 32wv..+31 (2 coltiles) x 4 rowtiles
#pragma unroll
  for (int rt = 0; rt < 4; ++rt)
#pragma unroll
    for (int ct = 0; ct < 2; ++ct) acc3[rt][ct] = f32x4{0.f, 0.f, 0.f, 0.f};

  for (int c = 0; c < 4; ++c) {
    __syncthreads();  // previous chunk's H2 reads done
    if (wv == c) {    // wave c owns H2 cols 64c..64c+63 in its acc2
#pragma unroll
      for (int ct = 0; ct < 4; ++ct) {
        float bias = b2[64 * c + 16 * ct + lr];
#pragma unroll
        for (int rt = 0; rt < 4; ++rt) {
#pragma unroll
          for (int r = 0; r < 4; ++r) {
            float v = fmaxf(acc2[rt][ct][r] + bias, 0.f) * BN_SC;
            unsigned short hs, ls;
            split2(v, hs, ls);
            int row = 16 * rt + 4 * lg + r;
            int colL = 16 * ct + lr;
            int idx = row * 64 + (((colL >> 3) ^ (row & 7)) * 8) + (colL & 7);
            H2h[idx] = hs;
            H2l[idx] = ls;
          }
        }
      }
    }
    __syncthreads();  // H2 chunk ready
#pragma unroll
    for (int kt = 0; kt < 2; ++kt) {
      bf16x8 ah[4], al[4];
#pragma unroll
      for (int rt = 0; rt < 4; ++rt) {
        int arow = 16 * rt + lr;
        int aidx = arow * 64 + ((4 * kt + lg) ^ (arow & 7)) * 8;
        ah[rt] = *(const bf16x8*)&H2h[aidx];
        al[rt] = *(const bf16x8*)&H2l[aidx];
      }
      int kg = 64 * c + 32 * kt + 8 * lg;
#pragma unroll
      for (int ct = 0; ct < 2; ++ct) {
        int col = 32 * wv + 16 * ct + lr;
        bf16x8 bh = *(const bf16x8*)(W3h + (size_t)col * 256 + kg);
        bf16x8 bl = *(const bf16x8*)(W3l + (size_t)col * 256 + kg);
#pragma unroll
        for (int rt = 0; rt < 4; ++rt) {
          acc3[rt][ct] = MFMA16(ah[rt], bh, acc3[rt][ct]);
          acc3[rt][ct] = MFMA16(ah[rt], bl, acc3[rt][ct]);
          acc3[rt][ct] = MFMA16(al[rt], bh, acc3[rt][ct]);
        }
      }
    }
  }
  __syncthreads();  // all H2 reads done; POOL (X/H1) now reusable as H3

  // H3 write (f32, +bias, no activation)
#pragma unroll
  for (int ct = 0; ct < 2; ++ct) {
    float bias = b3[32 * wv + 16 * ct + lr];
#pragma unroll
    for (int rt = 0; rt < 4; ++rt)
#pragma unroll
      for (int r = 0; r < 4; ++r)
        H3[(16 * rt + 4 * lg + r) * 128 + 32 * wv + 16 * ct + lr] = acc3[rt][ct][r] + bias;
  }
  __syncthreads();

  // cosine head: 8 threads per edge
  {
    int i = tid >> 3, j = tid & 7;
    const float* ra = &H3[(2 * i) * 128];
    const float* rb = &H3[(2 * i + 1) * 128];
    float dot = 0.f, s1 = 0.f, s2 = 0.f;
#pragma unroll
    for (int s = 0; s < 16; ++s) {
      float a = ra[j + 8 * s], b = rb[j + 8 * s];
      dot += a * b;
      s1 += a * a;
      s2 += b * b;
    }
#pragma unroll
    for (int m = 4; m >= 1; m >>= 1) {
      dot += __shfl_xor(dot, m);
      s1 += __shfl_xor(s1, m);
      s2 += __shfl_xor(s2, m);
    }
    if (j == 0) {
      float n1 = fmaxf(sqrtf(s1), 1e-8f);
      float n2 = fmaxf(sqrtf(s2), 1e-8f);
      float cosv = dot / (n1 * n2);
      ew[e0 + i] = (cosv + 1.f) * 0.5f;
    }
  }
}

// ======================= Laplacian weights =======================
__global__ __launch_bounds__(256) void k_deg(const int* __restrict__ rowi, const int* __restrict__ colv,
                                             const float* __restrict__ ew, float* __restrict__ deg) {
  int e = blockIdx.x * 256 + threadIdx.x;
  if (e < EE) {
    int r = rowi[e];
    float w = (r == colv[e]) ? 0.f : ew[e];
    atomicAdd(&deg[r], w);
  }
}
__global__ __launch_bounds__(256) void k_dinv(const float* __restrict__ deg, float* __restrict__ dinv) {
  int n = blockIdx.x * 256 + threadIdx.x;
  if (n < NN) { float d = deg[n]; dinv[n] = d > 0.f ? 1.f / sqrtf(d) : 0.f; }
}
__global__ __launch_bounds__(256) void k_lapw(const int* __restrict__ rowi, const int* __restrict__ colv,
                                              const float* __restrict__ ew, const float* __restrict__ dinv,
                                              float* __restrict__ lapw) {
  int e = blockIdx.x * 256 + threadIdx.x;
  if (e < EE) {
    int r = rowi[e], c = colv[e];
    float w = (r == c) ? 0.f : ew[e];
    lapw[e] = -dinv[r] * w * dinv[c];
  }
}

// ======================= Cheb propagation: out = alpha*(L@x) + beta*y =======================
template <int DIM>
__global__ __launch_bounds__(256) void k_prop(const float* __restrict__ x, int ldx,
                                              const float* __restrict__ y, int ldy,
                                              float alpha, float beta,
                                              float* __restrict__ outv, int ldo,
                                              const float* __restrict__ lapw,
                                              const int* __restrict__ rowi,
                                              const int* __restrict__ offs,
                                              const int* __restrict__ eid) {
  constexpr int NPB = 256 / DIM;
  int n = blockIdx.x * NPB + threadIdx.x / DIM;
  int f = threadIdx.x % DIM;
  if (n >= NN) return;
  float acc = 0.f;
  int j1 = offs[n + 1];
  for (int j = offs[n]; j < j1; ++j) {
    int e = eid[j];
    acc += lapw[e] * x[(size_t)rowi[e] * ldx + f];
  }
  float r = alpha * acc;
  if (beta != 0.f) r += beta * y[(size_t)n * ldy + f];
  outv[(size_t)n * ldo + f] = r;
}

// ======================= cheb combine: relu(sum_k txk @ Wk) -> jk slice =======================
template <int DK>
__global__ __launch_bounds__(512) void k_combine(const float* __restrict__ t0, int ld0,
                                                 const float* __restrict__ t1, int ld1,
                                                 const float* __restrict__ t2, int ld2,
                                                 const float* __restrict__ t3, int ld3,
                                                 const float* __restrict__ W,
                                                 float* __restrict__ outp) {
  int n = blockIdx.x * 8 + (threadIdx.x >> 6);
  int c = threadIdx.x & 63;
  if (n >= NN) return;
  const float* r0 = t0 + (size_t)n * ld0;
  const float* r1 = t1 + (size_t)n * ld1;
  const float* r2 = t2 + (size_t)n * ld2;
  const float* r3 = t3 + (size_t)n * ld3;
  const float* w0 = W;
  const float* w1 = W + DK * 64;
  const float* w2 = W + 2 * DK * 64;
  const float* w3 = W + 3 * DK * 64;
  float acc = 0.f;
#pragma unroll 4
  for (int d = 0; d < DK; ++d) {
    acc += r0[d] * w0[d * 64 + c];
    acc += r1[d] * w1[d * 64 + c];
    acc += r2[d] * w2[d * 64 + c];
    acc += r3[d] * w3[d * 64 + c];
  }
  outp[(size_t)n * 256 + c] = fmaxf(acc, 0.f);
}

// ======================= classifier head =======================
__global__ void k_tr256(const float* __restrict__ A, float* __restrict__ At) {
  int c = blockIdx.x, k = threadIdx.x;
  At[(size_t)k * 256 + c] = A[(size_t)c * 256 + k];
}

__global__ __launch_bounds__(256) void k_mlogit(const float* __restrict__ jk, const float* __restrict__ Wm1t,
                                                const float* __restrict__ bm1, const float* __restrict__ Wm2,
                                                const float* __restrict__ bm2, float* __restrict__ logit1) {
  __shared__ float jks[16 * 256];
  __shared__ float red[16 * 8];
  int tid = threadIdx.x, n0 = blockIdx.x * 16;
  {
    const float4* src = (const float4*)(jk + (size_t)n0 * 256);
    float4* dst = (float4*)jks;
#pragma unroll
    for (int u = 0; u < 4; ++u) dst[tid + 256 * u] = src[tid + 256 * u];
  }
  __syncthreads();
  int c = tid;
  float acc[16];
  float bb = bm1[c];
#pragma unroll
  for (int r = 0; r < 16; ++r) acc[r] = bb;
  for (int k = 0; k < 256; k += 4) {
    float w0 = Wm1t[(size_t)(k + 0) * 256 + c];
    float w1 = Wm1t[(size_t)(k + 1) * 256 + c];
    float w2 = Wm1t[(size_t)(k + 2) * 256 + c];
    float w3 = Wm1t[(size_t)(k + 3) * 256 + c];
#pragma unroll
    for (int r = 0; r < 16; ++r) {
      float4 jv = *(const float4*)&jks[r * 256 + k];
      acc[r] += jv.x * w0 + jv.y * w1 + jv.z * w2 + jv.w * w3;
    }
  }
  float w20 = Wm2[c], w21 = Wm2[256 + c];
  int wid = tid >> 6, lane = tid & 63;
#pragma unroll
  for (int r = 0; r < 16; ++r) {
    float mv = fmaxf(acc[r], 0.f) * BN_SC;
    float v0 = mv * w20, v1 = mv * w21;
#pragma unroll
    for (int m = 32; m >= 1; m >>= 1) {
      v0 += __shfl_xor(v0, m, 64);
      v1 += __shfl_xor(v1, m, 64);
    }
    if (lane == 0) { red[r * 8 + wid] = v0; red[r * 8 + 4 + wid] = v1; }
  }
  __syncthreads();
  if (tid < 32) {
    int r = tid >> 1, cls = tid & 1;
    float s = red[r * 8 + cls * 4] + red[r * 8 + cls * 4 + 1] + red[r * 8 + cls * 4 + 2] + red[r * 8 + cls * 4 + 3];
    logit1[(size_t)(n0 + r) * 2 + cls] = s + bm2[cls];
  }
}

// ======================= bys branch =======================
__global__ __launch_bounds__(256) void k_h0(const float* __restrict__ feat, const float* __restrict__ Wl,
                                            const float* __restrict__ bl, float* __restrict__ h0) {
  int idx = blockIdx.x * 256 + threadIdx.x;
  if (idx >= NN * 16) return;
  int n = idx >> 4, j = idx & 15;
  const float* fr = feat + (size_t)n * 128;
  const float* wr = Wl + (size_t)j * 128;
  float acc = bl[j];
#pragma unroll 8
  for (int d = 0; d < 128; d += 4) {
    float4 f = *(const float4*)(fr + d);
    float4 w = *(const float4*)(wr + d);
    acc += f.x * w.x + f.y * w.y + f.z * w.z + f.w * w.w;
  }
  h0[idx] = acc;
}

__global__ __launch_bounds__(256) void k_bys(const float* __restrict__ hprev, const float* __restrict__ nz,
                                             float* __restrict__ hout,
                                             const float* __restrict__ ew, const int* __restrict__ rowi,
                                             const int* __restrict__ offs, const int* __restrict__ eid) {
  int idx = blockIdx.x * 256 + threadIdx.x;
  int n = idx >> 4, f = idx & 15;
  if (n >= NN) return;
  float acc = 0.f;
  int j1 = offs[n + 1];
  for (int j = offs[n]; j < j1; ++j) {
    int e = eid[j];
    acc += ew[e] * hprev[(size_t)rowi[e] * 16 + f];
  }
  hout[idx] = nz[idx] + acc;
}

// ======================= final: logit2 + softmaxes + max =======================
__global__ __launch_bounds__(256) void k_final(const float* __restrict__ states, const float* __restrict__ Whl,
                                               const float* __restrict__ bhl, const float* __restrict__ logit1,
                                               float* __restrict__ outp) {
  int n = blockIdx.x * 4 + (threadIdx.x >> 6);
  int l = threadIdx.x & 63;
  if (n >= NN) return;
  const float* sf = states + (size_t)n * 400;  // row-major reshape of [25][N][16]
  float a0 = 0.f, a1 = 0.f;
  for (int t = l; t < 400; t += 64) {
    float v = sf[t];
    a0 += v * Whl[t];
    a1 += v * Whl[400 + t];
  }
#pragma unroll
  for (int m = 32; m >= 1; m >>= 1) {
    a0 += __shfl_xor(a0, m, 64);
    a1 += __shfl_xor(a1, m, 64);
  }
  if (l == 0) {
    float z0 = 1.f / (1.f + expf(-(a0 + bhl[0])));
    float z1 = 1.f / (1.f + expf(-(a1 + bhl[1])));
    float p20 = 1.f / (1.f + expf(z1 - z0));
    float p21 = 1.f - p20;
    float l10 = logit1[(size_t)n * 2], l11 = logit1[(size_t)n * 2 + 1];
    float p10 = 1.f / (1.f + expf(l11 - l10));
    float p11 = 1.f - p10;
    outp[(size_t)n * 2] = p10;
    outp[(size_t)n * 2 + 1] = p11;
    outp[2 * NN + (size_t)n * 2] = p20;
    outp[2 * NN + (size_t)n * 2 + 1] = p21;
    outp[4 * NN + (size_t)n * 2] = fmaxf(p10, p20);
    outp[4 * NN + (size_t)n * 2 + 1] = fmaxf(p11, p21);
  }
}

// ======================= host =======================
extern "C" void kernel_launch(void* const* d_in, const int* in_sizes, int n_in,
                              void* d_out, int out_size, void* d_ws, size_t ws_size,
                              hipStream_t stream) {
  const float* feat = (const float*)d_in[0];
  const int* ei = (const int*)d_in[1];
  const float* xen = (const float*)d_in[2];
  const float* We1 = (const float*)d_in[3];
  const float* be1 = (const float*)d_in[4];
  const float* We2 = (const float*)d_in[5];
  const float* be2 = (const float*)d_in[6];
  const float* We3 = (const float*)d_in[7];
  const float* be3 = (const float*)d_in[8];
  const float* cw[4] = {(const float*)d_in[9], (const float*)d_in[10], (const float*)d_in[11], (const float*)d_in[12]};
  const float* Wm1 = (const float*)d_in[13];
  const float* bm1 = (const float*)d_in[14];
  const float* Wm2 = (const float*)d_in[15];
  const float* bm2 = (const float*)d_in[16];
  const float* Wl = (const float*)d_in[17];
  const float* bl = (const float*)d_in[18];
  const float* Whl = (const float*)d_in[19];
  const float* bhl = (const float*)d_in[20];
  const float* noise = (const float*)d_in[21];
  float* outp = (float*)d_out;

  char* wp_ = (char*)d_ws;
  auto alloc = [&](size_t bytes) {
    char* p = wp_;
    wp_ += (bytes + 255) & ~(size_t)255;
    return p;
  };
  float* ew = (float*)alloc((size_t)EE * 4);
  float* lapw = (float*)alloc((size_t)EE * 4);
  float* deg = (float*)alloc((size_t)NN * 4);
  float* dinv = (float*)alloc((size_t)NN * 4);
  int* cnt = (int*)alloc((size_t)NN * 4);
  int* offs = (int*)alloc((size_t)(NN + 1) * 4);
  int* eid = (int*)alloc((size_t)EE * 4);
  float* tx1 = (float*)alloc((size_t)NN * 128 * 4);
  float* tx2 = (float*)alloc((size_t)NN * 128 * 4);
  float* tx3 = (float*)alloc((size_t)NN * 128 * 4);
  float* jk = (float*)alloc((size_t)NN * 256 * 4);
  float* logit1 = (float*)alloc((size_t)NN * 2 * 4);
  float* Wm1t = (float*)alloc((size_t)256 * 256 * 4);
  float* h0 = (float*)alloc((size_t)NN * 16 * 4);
  float* states = (float*)alloc((size_t)25 * NN * 16 * 4);
  unsigned short* W1h = (unsigned short*)alloc((size_t)32768 * 2);
  unsigned short* W1l = (unsigned short*)alloc((size_t)32768 * 2);
  unsigned short* W2h = (unsigned short*)alloc((size_t)131072 * 2);
  unsigned short* W2l = (unsigned short*)alloc((size_t)131072 * 2);
  unsigned short* W3h = (unsigned short*)alloc((size_t)32768 * 2);
  unsigned short* W3l = (unsigned short*)alloc((size_t)32768 * 2);

  const int* rowi = ei;
  const int* colv = ei + EE;

  // weight splits (independent of everything else)
  k_wsplit<<<128, 256, 0, stream>>>(We1, W1h, W1l, 32768);
  k_wsplit<<<512, 256, 0, stream>>>(We2, W2h, W2l, 131072);
  k_wsplit<<<128, 256, 0, stream>>>(We3, W3h, W3l, 32768);

  hipMemsetAsync(cnt, 0, (size_t)NN * 4, stream);
  hipMemsetAsync(deg, 0, (size_t)NN * 4, stream);
  k_count<<<1250, 256, 0, stream>>>(colv, cnt);
  k_scan<<<1, 1024, 0, stream>>>(cnt, offs);
  hipMemsetAsync(cnt, 0, (size_t)NN * 4, stream);
  k_fill<<<1250, 256, 0, stream>>>(colv, offs, cnt, eid);
  k_sort<<<79, 256, 0, stream>>>(offs, eid);

  k_edge_mlp<<<10000, 256, 0, stream>>>(xen, W1h, W1l, be1, W2h, W2l, be2, W3h, W3l, be3, ew);

  k_deg<<<1250, 256, 0, stream>>>(rowi, colv, ew, deg);
  k_dinv<<<79, 256, 0, stream>>>(deg, dinv);
  k_lapw<<<1250, 256, 0, stream>>>(rowi, colv, ew, dinv, lapw);
  k_tr256<<<256, 256, 0, stream>>>(Wm1, Wm1t);

  // cheb layer 0 (input dim 128)
  k_prop<128><<<10000, 256, 0, stream>>>(feat, 128, feat, 128, 1.f, 0.f, tx1, 128, lapw, rowi, offs, eid);
  k_prop<128><<<10000, 256, 0, stream>>>(tx1, 128, feat, 128, 2.f, -1.f, tx2, 128, lapw, rowi, offs, eid);
  k_prop<128><<<10000, 256, 0, stream>>>(tx2, 128, tx1, 128, 2.f, -1.f, tx3, 128, lapw, rowi, offs, eid);
  k_combine<128><<<2500, 512, 0, stream>>>(feat, 128, tx1, 128, tx2, 128, tx3, 128, cw[0], jk);
  // cheb layers 1..3 (input dim 64, read from jk slice)
  for (int l = 1; l < 4; ++l) {
    const float* xin = jk + (l - 1) * 64;
    k_prop<64><<<5000, 256, 0, stream>>>(xin, 256, xin, 256, 1.f, 0.f, tx1, 64, lapw, rowi, offs, eid);
    k_prop<64><<<5000, 256, 0, stream>>>(tx1, 64, xin, 256, 2.f, -1.f, tx2, 64, lapw, rowi, offs, eid);
    k_prop<64><<<5000, 256, 0, stream>>>(tx2, 64, tx1, 64, 2.f, -1.f, tx3, 64, lapw, rowi, offs, eid);
    k_combine<64><<<2500, 512, 0, stream>>>(xin, 256, tx1, 64, tx2, 64, tx3, 64, cw[l], jk + l * 64);
  }
  k_mlogit<<<1250, 256, 0, stream>>>(jk, Wm1t, bm1, Wm2, bm2, logit1);

  k_h0<<<1250, 256, 0, stream>>>(feat, Wl, bl, h0);
  const float* hprev = h0;
  for (int s = 0; s < 25; ++s) {
    float* hout = states + (size_t)s * NN * 16;
    k_bys<<<1250, 256, 0, stream>>>(hprev, noise + (size_t)s * NN * 16, hout, ew, rowi, offs, eid);
    hprev = hout;
  }
  k_final<<<5000, 256, 0, stream>>>(states, Whl, bhl, logit1, outp);
}

// Round 3
// 3322.697 us; speedup vs baseline: 2.9581x; 1.1213x over previous
//
#include <hip/hip_runtime.h>
#include <math.h>

#define NN 20000
#define EE 320000
#define BN_SC 0.9999950000374997f

typedef __attribute__((ext_vector_type(8))) short bf16x8;
typedef __attribute__((ext_vector_type(4))) float f32x4;

__device__ __forceinline__ unsigned short f2b(float x) {
  unsigned int u = __builtin_bit_cast(unsigned int, x);
  u += 0x7FFFu + ((u >> 16) & 1u);
  return (unsigned short)(u >> 16);
}
__device__ __forceinline__ void split2(float x, unsigned short& h, unsigned short& l) {
  h = f2b(x);
  float hf = __builtin_bit_cast(float, (unsigned int)h << 16);
  l = f2b(x - hf);
}

// ======================= weight split prep =======================
__global__ __launch_bounds__(256) void k_wsplit(const float* __restrict__ W, unsigned short* __restrict__ Wh,
                                                unsigned short* __restrict__ Wl, int n) {
  int i = blockIdx.x * 256 + threadIdx.x;
  if (i < n) split2(W[i], Wh[i], Wl[i]);
}

// ======================= CSR build (by destination col) =======================
__global__ __launch_bounds__(256) void k_count(const int* __restrict__ colv, int* __restrict__ cnt) {
  int e = blockIdx.x * 256 + threadIdx.x;
  if (e < EE) atomicAdd(&cnt[colv[e]], 1);
}

__global__ __launch_bounds__(1024) void k_scan(const int* __restrict__ cnt, int* __restrict__ offs) {
  __shared__ int sb[1024];
  __shared__ int sc;
  int t = threadIdx.x;
  if (t == 0) { sc = 0; offs[0] = 0; }
  __syncthreads();
  for (int base = 0; base < NN; base += 1024) {
    int v = (base + t < NN) ? cnt[base + t] : 0;
    sb[t] = v;
    __syncthreads();
    for (int off = 1; off < 1024; off <<= 1) {
      int x = (t >= off) ? sb[t - off] : 0;
      __syncthreads();
      sb[t] += x;
      __syncthreads();
    }
    if (base + t < NN) offs[base + t + 1] = sc + sb[t];
    __syncthreads();
    if (t == 0) sc += sb[1023];
    __syncthreads();
  }
}

__global__ __launch_bounds__(256) void k_fill(const int* __restrict__ colv, const int* __restrict__ offs,
                                              int* __restrict__ cur, int* __restrict__ eid) {
  int e = blockIdx.x * 256 + threadIdx.x;
  if (e < EE) {
    int d = colv[e];
    int p = atomicAdd(&cur[d], 1);
    eid[offs[d] + p] = e;
  }
}

__global__ __launch_bounds__(256) void k_sort(const int* __restrict__ offs, int* __restrict__ eid) {
  int n = blockIdx.x * 256 + threadIdx.x;
  if (n >= NN) return;
  int j0 = offs[n], j1 = offs[n + 1];
  for (int i = j0 + 1; i < j1; ++i) {
    int v = eid[i];
    int j = i - 1;
    while (j >= j0 && eid[j] > v) { eid[j + 1] = eid[j]; --j; }
    eid[j + 1] = v;
  }
}

// pack (weight, src_row) per CSR slot: sequential 8B reads in the hot loops
__global__ __launch_bounds__(256) void k_pack(const int* __restrict__ eid, const int* __restrict__ rowi,
                                              const float* __restrict__ ew, const float* __restrict__ lapw,
                                              float2* __restrict__ packW, float2* __restrict__ packL) {
  int j = blockIdx.x * 256 + threadIdx.x;
  if (j < EE) {
    int e = eid[j];
    float r = __int_as_float(rowi[e]);
    packW[j] = make_float2(ew[e], r);
    packL[j] = make_float2(lapw[e], r);
  }
}

// ======================= fused edge MLP (MFMA split-bf16) + cosine =======================
// 32 edges (64 rows, halves interleaved) per block, 256 threads = 4 waves.
// amdgpu_waves_per_eu(2,2): pin exactly 2 waves/EU so the allocator gets the full
// 256-VGPR budget (acc2 64 + acc3 32 + fragments) — round-2 spilled 330MB to scratch
// because the heuristic targeted 3 waves/EU off the 48KB LDS footprint.
#define MFMA16(a, b, c) __builtin_amdgcn_mfma_f32_16x16x32_bf16(a, b, c, 0, 0, 0)

__global__ __launch_bounds__(256) __attribute__((amdgpu_waves_per_eu(2, 2))) void k_edge_mlp(
    const float* __restrict__ X,
    const unsigned short* __restrict__ W1h, const unsigned short* __restrict__ W1l, const float* __restrict__ b1,
    const unsigned short* __restrict__ W2h, const unsigned short* __restrict__ W2l, const float* __restrict__ b2,
    const unsigned short* __restrict__ W3h, const unsigned short* __restrict__ W3l, const float* __restrict__ b3,
    float* __restrict__ ew) {
  __shared__ __align__(16) unsigned short POOL[4 * 4096];
  __shared__ __align__(16) unsigned short H2h[4096], H2l[4096];
  unsigned short* Xh = POOL;
  unsigned short* Xl = POOL + 4096;
  unsigned short* H1h = POOL + 8192;
  unsigned short* H1l = POOL + 12288;
  float* H3 = (float*)POOL;  // 64*128 f32 = 32KB, aliases X/H1 planes (dead by then)

  const int tid = threadIdx.x;
  const int wv = tid >> 6;
  const int lane = tid & 63;
  const int lr = lane & 15;
  const int lg = lane >> 4;
  const int e0 = blockIdx.x * 32;

  // ---- stage X[64 rows][64 cols] as split bf16, swizzled ----
  {
    int row = tid >> 2, cq = tid & 3;
    const float* src = X + (size_t)(e0 + (row >> 1)) * 128 + (row & 1) * 64 + cq * 16;
#pragma unroll
    for (int half = 0; half < 2; ++half) {
      float4 a = ((const float4*)src)[2 * half];
      float4 b = ((const float4*)src)[2 * half + 1];
      float vals[8] = {a.x, a.y, a.z, a.w, b.x, b.y, b.z, b.w};
      unsigned short hs[8], ls[8];
#pragma unroll
      for (int j = 0; j < 8; ++j) split2(vals[j], hs[j], ls[j]);
      int chunk = (2 * cq + half) ^ (row & 7);
      int idx = row * 64 + chunk * 8;
#pragma unroll
      for (int j = 0; j < 8; ++j) { Xh[idx + j] = hs[j]; Xl[idx + j] = ls[j]; }
    }
  }
  __syncthreads();

  f32x4 acc2[4][4];
#pragma unroll
  for (int rt = 0; rt < 4; ++rt)
#pragma unroll
    for (int ct = 0; ct < 4; ++ct) acc2[rt][ct] = f32x4{0.f, 0.f, 0.f, 0.f};

  // ===== phases A+B: 8 chunks of 64 H1-cols =====
  for (int kc = 0; kc < 8; ++kc) {
    f32x4 acc1[4];
#pragma unroll
    for (int ct = 0; ct < 4; ++ct) acc1[ct] = f32x4{0.f, 0.f, 0.f, 0.f};
#pragma unroll
    for (int kt = 0; kt < 2; ++kt) {
      int arow = 16 * wv + lr;
      int aidx = arow * 64 + ((4 * kt + lg) ^ (arow & 7)) * 8;
      bf16x8 ah = *(const bf16x8*)&Xh[aidx];
      bf16x8 al = *(const bf16x8*)&Xl[aidx];
      int kk = 32 * kt + 8 * lg;
#pragma unroll
      for (int ct = 0; ct < 4; ++ct) {
        int col = 64 * kc + 16 * ct + lr;
        bf16x8 bh = *(const bf16x8*)(W1h + (size_t)col * 64 + kk);
        bf16x8 bl = *(const bf16x8*)(W1l + (size_t)col * 64 + kk);
        acc1[ct] = MFMA16(ah, bh, acc1[ct]);
        acc1[ct] = MFMA16(ah, bl, acc1[ct]);
        acc1[ct] = MFMA16(al, bh, acc1[ct]);
      }
    }
    __syncthreads();
#pragma unroll
    for (int ct = 0; ct < 4; ++ct) {
      float bias = b1[64 * kc + 16 * ct + lr];
#pragma unroll
      for (int r = 0; r < 4; ++r) {
        float v = fmaxf(acc1[ct][r] + bias, 0.f) * BN_SC;
        unsigned short hs, ls;
        split2(v, hs, ls);
        int row = 16 * wv + 4 * lg + r;
        int colL = 16 * ct + lr;
        int idx = row * 64 + (((colL >> 3) ^ (row & 7)) * 8) + (colL & 7);
        H1h[idx] = hs;
        H1l[idx] = ls;
      }
    }
    __syncthreads();
#pragma unroll
    for (int kt = 0; kt < 2; ++kt) {
      bf16x8 ah[4], al[4];
#pragma unroll
      for (int rt = 0; rt < 4; ++rt) {
        int arow = 16 * rt + lr;
        int aidx = arow * 64 + ((4 * kt + lg) ^ (arow & 7)) * 8;
        ah[rt] = *(const bf16x8*)&H1h[aidx];
        al[rt] = *(const bf16x8*)&H1l[aidx];
      }
      int kg = 64 * kc + 32 * kt + 8 * lg;
#pragma unroll
      for (int ct = 0; ct < 4; ++ct) {
        int col = 64 * wv + 16 * ct + lr;
        bf16x8 bh = *(const bf16x8*)(W2h + (size_t)col * 512 + kg);
        bf16x8 bl = *(const bf16x8*)(W2l + (size_t)col * 512 + kg);
#pragma unroll
        for (int rt = 0; rt < 4; ++rt) {
          acc2[rt][ct] = MFMA16(ah[rt], bh, acc2[rt][ct]);
          acc2[rt][ct] = MFMA16(ah[rt], bl, acc2[rt][ct]);
          acc2[rt][ct] = MFMA16(al[rt], bh, acc2[rt][ct]);
        }
      }
    }
  }

  // ===== phase C: layer 3 via 4 H2 chunks of 64 cols =====
  f32x4 acc3[4][2];
#pragma unroll
  for (int rt = 0; rt < 4; ++rt)
#pragma unroll
    for (int ct = 0; ct < 2; ++ct) acc3[rt][ct] = f32x4{0.f, 0.f, 0.f, 0.f};

  for (int c = 0; c < 4; ++c) {
    __syncthreads();
    if (wv == c) {
#pragma unroll
      for (int ct = 0; ct < 4; ++ct) {
        float bias = b2[64 * c + 16 * ct + lr];
#pragma unroll
        for (int rt = 0; rt < 4; ++rt) {
#pragma unroll
          for (int r = 0; r < 4; ++r) {
            float v = fmaxf(acc2[rt][ct][r] + bias, 0.f) * BN_SC;
            unsigned short hs, ls;
            split2(v, hs, ls);
            int row = 16 * rt + 4 * lg + r;
            int colL = 16 * ct + lr;
            int idx = row * 64 + (((colL >> 3) ^ (row & 7)) * 8) + (colL & 7);
            H2h[idx] = hs;
            H2l[idx] = ls;
          }
        }
      }
    }
    __syncthreads();
#pragma unroll
    for (int kt = 0; kt < 2; ++kt) {
      bf16x8 ah[4], al[4];
#pragma unroll
      for (int rt = 0; rt < 4; ++rt) {
        int arow = 16 * rt + lr;
        int aidx = arow * 64 + ((4 * kt + lg) ^ (arow & 7)) * 8;
        ah[rt] = *(const bf16x8*)&H2h[aidx];
        al[rt] = *(const bf16x8*)&H2l[aidx];
      }
      int kg = 64 * c + 32 * kt + 8 * lg;
#pragma unroll
      for (int ct = 0; ct < 2; ++ct) {
        int col = 32 * wv + 16 * ct + lr;
        bf16x8 bh = *(const bf16x8*)(W3h + (size_t)col * 256 + kg);
        bf16x8 bl = *(const bf16x8*)(W3l + (size_t)col * 256 + kg);
#pragma unroll
        for (int rt = 0; rt < 4; ++rt) {
          acc3[rt][ct] = MFMA16(ah[rt], bh, acc3[rt][ct]);
          acc3[rt][ct] = MFMA16(ah[rt], bl, acc3[rt][ct]);
          acc3[rt][ct] = MFMA16(al[rt], bh, acc3[rt][ct]);
        }
      }
    }
  }
  __syncthreads();

#pragma unroll
  for (int ct = 0; ct < 2; ++ct) {
    float bias = b3[32 * wv + 16 * ct + lr];
#pragma unroll
    for (int rt = 0; rt < 4; ++rt)
#pragma unroll
      for (int r = 0; r < 4; ++r)
        H3[(16 * rt + 4 * lg + r) * 128 + 32 * wv + 16 * ct + lr] = acc3[rt][ct][r] + bias;
  }
  __syncthreads();

  // cosine head: 8 threads per edge
  {
    int i = tid >> 3, j = tid & 7;
    const float* ra = &H3[(2 * i) * 128];
    const float* rb = &H3[(2 * i + 1) * 128];
    float dot = 0.f, s1 = 0.f, s2 = 0.f;
#pragma unroll
    for (int s = 0; s < 16; ++s) {
      float a = ra[j + 8 * s], b = rb[j + 8 * s];
      dot += a * b;
      s1 += a * a;
      s2 += b * b;
    }
#pragma unroll
    for (int m = 4; m >= 1; m >>= 1) {
      dot += __shfl_xor(dot, m);
      s1 += __shfl_xor(s1, m);
      s2 += __shfl_xor(s2, m);
    }
    if (j == 0) {
      float n1 = fmaxf(sqrtf(s1), 1e-8f);
      float n2 = fmaxf(sqrtf(s2), 1e-8f);
      float cosv = dot / (n1 * n2);
      ew[e0 + i] = (cosv + 1.f) * 0.5f;
    }
  }
}

// ======================= Laplacian weights =======================
__global__ __launch_bounds__(256) void k_deg(const int* __restrict__ rowi, const int* __restrict__ colv,
                                             const float* __restrict__ ew, float* __restrict__ deg) {
  int e = blockIdx.x * 256 + threadIdx.x;
  if (e < EE) {
    int r = rowi[e];
    float w = (r == colv[e]) ? 0.f : ew[e];
    atomicAdd(&deg[r], w);
  }
}
__global__ __launch_bounds__(256) void k_dinv(const float* __restrict__ deg, float* __restrict__ dinv) {
  int n = blockIdx.x * 256 + threadIdx.x;
  if (n < NN) { float d = deg[n]; dinv[n] = d > 0.f ? 1.f / sqrtf(d) : 0.f; }
}
__global__ __launch_bounds__(256) void k_lapw(const int* __restrict__ rowi, const int* __restrict__ colv,
                                              const float* __restrict__ ew, const float* __restrict__ dinv,
                                              float* __restrict__ lapw) {
  int e = blockIdx.x * 256 + threadIdx.x;
  if (e < EE) {
    int r = rowi[e], c = colv[e];
    float w = (r == c) ? 0.f : ew[e];
    lapw[e] = -dinv[r] * w * dinv[c];
  }
}

// ======================= Cheb propagation: out = alpha*(L@x) + beta*y =======================
template <int DIM>
__global__ __launch_bounds__(256) void k_prop(const float* __restrict__ x, int ldx,
                                              const float* __restrict__ y, int ldy,
                                              float alpha, float beta,
                                              float* __restrict__ outv, int ldo,
                                              const float2* __restrict__ packL,
                                              const int* __restrict__ offs) {
  constexpr int NPB = 256 / DIM;
  int n = blockIdx.x * NPB + threadIdx.x / DIM;
  int f = threadIdx.x % DIM;
  if (n >= NN) return;
  float acc = 0.f;
  int j1 = offs[n + 1];
  for (int j = offs[n]; j < j1; ++j) {
    float2 p = packL[j];
    acc += p.x * x[(size_t)__float_as_int(p.y) * ldx + f];
  }
  float r = alpha * acc;
  if (beta != 0.f) r += beta * y[(size_t)n * ldy + f];
  outv[(size_t)n * ldo + f] = r;
}

// ======================= cheb combine: relu(sum_k txk @ Wk) -> jk slice =======================
template <int DK>
__global__ __launch_bounds__(512) void k_combine(const float* __restrict__ t0, int ld0,
                                                 const float* __restrict__ t1, int ld1,
                                                 const float* __restrict__ t2, int ld2,
                                                 const float* __restrict__ t3, int ld3,
                                                 const float* __restrict__ W,
                                                 float* __restrict__ outp) {
  int n = blockIdx.x * 8 + (threadIdx.x >> 6);
  int c = threadIdx.x & 63;
  if (n >= NN) return;
  const float* r0 = t0 + (size_t)n * ld0;
  const float* r1 = t1 + (size_t)n * ld1;
  const float* r2 = t2 + (size_t)n * ld2;
  const float* r3 = t3 + (size_t)n * ld3;
  const float* w0 = W;
  const float* w1 = W + DK * 64;
  const float* w2 = W + 2 * DK * 64;
  const float* w3 = W + 3 * DK * 64;
  float acc = 0.f;
#pragma unroll 4
  for (int d = 0; d < DK; ++d) {
    acc += r0[d] * w0[d * 64 + c];
    acc += r1[d] * w1[d * 64 + c];
    acc += r2[d] * w2[d * 64 + c];
    acc += r3[d] * w3[d * 64 + c];
  }
  outp[(size_t)n * 256 + c] = fmaxf(acc, 0.f);
}

// ======================= classifier head =======================
__global__ void k_tr256(const float* __restrict__ A, float* __restrict__ At) {
  int c = blockIdx.x, k = threadIdx.x;
  At[(size_t)k * 256 + c] = A[(size_t)c * 256 + k];
}

__global__ __launch_bounds__(256) void k_mlogit(const float* __restrict__ jk, const float* __restrict__ Wm1t,
                                                const float* __restrict__ bm1, const float* __restrict__ Wm2,
                                                const float* __restrict__ bm2, float* __restrict__ logit1) {
  __shared__ float jks[16 * 256];
  __shared__ float red[16 * 8];
  int tid = threadIdx.x, n0 = blockIdx.x * 16;
  {
    const float4* src = (const float4*)(jk + (size_t)n0 * 256);
    float4* dst = (float4*)jks;
#pragma unroll
    for (int u = 0; u < 4; ++u) dst[tid + 256 * u] = src[tid + 256 * u];
  }
  __syncthreads();
  int c = tid;
  float acc[16];
  float bb = bm1[c];
#pragma unroll
  for (int r = 0; r < 16; ++r) acc[r] = bb;
  for (int k = 0; k < 256; k += 4) {
    float w0 = Wm1t[(size_t)(k + 0) * 256 + c];
    float w1 = Wm1t[(size_t)(k + 1) * 256 + c];
    float w2 = Wm1t[(size_t)(k + 2) * 256 + c];
    float w3 = Wm1t[(size_t)(k + 3) * 256 + c];
#pragma unroll
    for (int r = 0; r < 16; ++r) {
      float4 jv = *(const float4*)&jks[r * 256 + k];
      acc[r] += jv.x * w0 + jv.y * w1 + jv.z * w2 + jv.w * w3;
    }
  }
  float w20 = Wm2[c], w21 = Wm2[256 + c];
  int wid = tid >> 6, lane = tid & 63;
#pragma unroll
  for (int r = 0; r < 16; ++r) {
    float mv = fmaxf(acc[r], 0.f) * BN_SC;
    float v0 = mv * w20, v1 = mv * w21;
#pragma unroll
    for (int m = 32; m >= 1; m >>= 1) {
      v0 += __shfl_xor(v0, m, 64);
      v1 += __shfl_xor(v1, m, 64);
    }
    if (lane == 0) { red[r * 8 + wid] = v0; red[r * 8 + 4 + wid] = v1; }
  }
  __syncthreads();
  if (tid < 32) {
    int r = tid >> 1, cls = tid & 1;
    float s = red[r * 8 + cls * 4] + red[r * 8 + cls * 4 + 1] + red[r * 8 + cls * 4 + 2] + red[r * 8 + cls * 4 + 3];
    logit1[(size_t)(n0 + r) * 2 + cls] = s + bm2[cls];
  }
}

// ======================= bys branch =======================
__global__ __launch_bounds__(256) void k_h0(const float* __restrict__ feat, const float* __restrict__ Wl,
                                            const float* __restrict__ bl, float* __restrict__ h0) {
  int idx = blockIdx.x * 256 + threadIdx.x;
  if (idx >= NN * 16) return;
  int n = idx >> 4, j = idx & 15;
  const float* fr = feat + (size_t)n * 128;
  const float* wr = Wl + (size_t)j * 128;
  float acc = bl[j];
#pragma unroll 8
  for (int d = 0; d < 128; d += 4) {
    float4 f = *(const float4*)(fr + d);
    float4 w = *(const float4*)(wr + d);
    acc += f.x * w.x + f.y * w.y + f.z * w.z + f.w * w.w;
  }
  h0[idx] = acc;
}

__global__ __launch_bounds__(256) void k_bys(const float* __restrict__ hprev, const float* __restrict__ nz,
                                             float* __restrict__ hout,
                                             const float2* __restrict__ packW,
                                             const int* __restrict__ offs) {
  int idx = blockIdx.x * 256 + threadIdx.x;
  int n = idx >> 4, f = idx & 15;
  if (n >= NN) return;
  float acc = 0.f;
  int j1 = offs[n + 1];
  for (int j = offs[n]; j < j1; ++j) {
    float2 p = packW[j];
    acc += p.x * hprev[(size_t)__float_as_int(p.y) * 16 + f];
  }
  hout[idx] = nz[idx] + acc;
}

// ======================= final: logit2 + softmaxes + max =======================
__global__ __launch_bounds__(256) void k_final(const float* __restrict__ states, const float* __restrict__ Whl,
                                               const float* __restrict__ bhl, const float* __restrict__ logit1,
                                               float* __restrict__ outp) {
  int n = blockIdx.x * 4 + (threadIdx.x >> 6);
  int l = threadIdx.x & 63;
  if (n >= NN) return;
  const float* sf = states + (size_t)n * 400;
  float a0 = 0.f, a1 = 0.f;
  for (int t = l; t < 400; t += 64) {
    float v = sf[t];
    a0 += v * Whl[t];
    a1 += v * Whl[400 + t];
  }
#pragma unroll
  for (int m = 32; m >= 1; m >>= 1) {
    a0 += __shfl_xor(a0, m, 64);
    a1 += __shfl_xor(a1, m, 64);
  }
  if (l == 0) {
    float z0 = 1.f / (1.f + expf(-(a0 + bhl[0])));
    float z1 = 1.f / (1.f + expf(-(a1 + bhl[1])));
    float p20 = 1.f / (1.f + expf(z1 - z0));
    float p21 = 1.f - p20;
    float l10 = logit1[(size_t)n * 2], l11 = logit1[(size_t)n * 2 + 1];
    float p10 = 1.f / (1.f + expf(l11 - l10));
    float p11 = 1.f - p10;
    outp[(size_t)n * 2] = p10;
    outp[(size_t)n * 2 + 1] = p11;
    outp[2 * NN + (size_t)n * 2] = p20;
    outp[2 * NN + (size_t)n * 2 + 1] = p21;
    outp[4 * NN + (size_t)n * 2] = fmaxf(p10, p20);
    outp[4 * NN + (size_t)n * 2 + 1] = fmaxf(p11, p21);
  }
}

// ======================= host =======================
extern "C" void kernel_launch(void* const* d_in, const int* in_sizes, int n_in,
                              void* d_out, int out_size, void* d_ws, size_t ws_size,
                              hipStream_t stream) {
  const float* feat = (const float*)d_in[0];
  const int* ei = (const int*)d_in[1];
  const float* xen = (const float*)d_in[2];
  const float* We1 = (const float*)d_in[3];
  const float* be1 = (const float*)d_in[4];
  const float* We2 = (const float*)d_in[5];
  const float* be2 = (const float*)d_in[6];
  const float* We3 = (const float*)d_in[7];
  const float* be3 = (const float*)d_in[8];
  const float* cw[4] = {(const float*)d_in[9], (const float*)d_in[10], (const float*)d_in[11], (const float*)d_in[12]};
  const float* Wm1 = (const float*)d_in[13];
  const float* bm1 = (const float*)d_in[14];
  const float* Wm2 = (const float*)d_in[15];
  const float* bm2 = (const float*)d_in[16];
  const float* Wl = (const float*)d_in[17];
  const float* bl = (const float*)d_in[18];
  const float* Whl = (const float*)d_in[19];
  const float* bhl = (const float*)d_in[20];
  const float* noise = (const float*)d_in[21];
  float* outp = (float*)d_out;

  char* wp_ = (char*)d_ws;
  auto alloc = [&](size_t bytes) {
    char* p = wp_;
    wp_ += (bytes + 255) & ~(size_t)255;
    return p;
  };
  float* ew = (float*)alloc((size_t)EE * 4);
  float* lapw = (float*)alloc((size_t)EE * 4);
  float* deg = (float*)alloc((size_t)NN * 4);
  float* dinv = (float*)alloc((size_t)NN * 4);
  int* cnt = (int*)alloc((size_t)NN * 4);
  int* offs = (int*)alloc((size_t)(NN + 1) * 4);
  int* eid = (int*)alloc((size_t)EE * 4);
  float2* packW = (float2*)alloc((size_t)EE * 8);
  float2* packL = (float2*)alloc((size_t)EE * 8);
  float* tx1 = (float*)alloc((size_t)NN * 128 * 4);
  float* tx2 = (float*)alloc((size_t)NN * 128 * 4);
  float* tx3 = (float*)alloc((size_t)NN * 128 * 4);
  float* jk = (float*)alloc((size_t)NN * 256 * 4);
  float* logit1 = (float*)alloc((size_t)NN * 2 * 4);
  float* Wm1t = (float*)alloc((size_t)256 * 256 * 4);
  float* h0 = (float*)alloc((size_t)NN * 16 * 4);
  float* states = (float*)alloc((size_t)25 * NN * 16 * 4);
  unsigned short* W1h = (unsigned short*)alloc((size_t)32768 * 2);
  unsigned short* W1l = (unsigned short*)alloc((size_t)32768 * 2);
  unsigned short* W2h = (unsigned short*)alloc((size_t)131072 * 2);
  unsigned short* W2l = (unsigned short*)alloc((size_t)131072 * 2);
  unsigned short* W3h = (unsigned short*)alloc((size_t)32768 * 2);
  unsigned short* W3l = (unsigned short*)alloc((size_t)32768 * 2);

  const int* rowi = ei;
  const int* colv = ei + EE;

  k_wsplit<<<128, 256, 0, stream>>>(We1, W1h, W1l, 32768);
  k_wsplit<<<512, 256, 0, stream>>>(We2, W2h, W2l, 131072);
  k_wsplit<<<128, 256, 0, stream>>>(We3, W3h, W3l, 32768);

  hipMemsetAsync(cnt, 0, (size_t)NN * 4, stream);
  hipMemsetAsync(deg, 0, (size_t)NN * 4, stream);
  k_count<<<1250, 256, 0, stream>>>(colv, cnt);
  k_scan<<<1, 1024, 0, stream>>>(cnt, offs);
  hipMemsetAsync(cnt, 0, (size_t)NN * 4, stream);
  k_fill<<<1250, 256, 0, stream>>>(colv, offs, cnt, eid);
  k_sort<<<79, 256, 0, stream>>>(offs, eid);

  k_edge_mlp<<<10000, 256, 0, stream>>>(xen, W1h, W1l, be1, W2h, W2l, be2, W3h, W3l, be3, ew);

  k_deg<<<1250, 256, 0, stream>>>(rowi, colv, ew, deg);
  k_dinv<<<79, 256, 0, stream>>>(deg, dinv);
  k_lapw<<<1250, 256, 0, stream>>>(rowi, colv, ew, dinv, lapw);
  k_pack<<<1250, 256, 0, stream>>>(eid, rowi, ew, lapw, packW, packL);
  k_tr256<<<256, 256, 0, stream>>>(Wm1, Wm1t);

  // cheb layer 0 (input dim 128)
  k_prop<128><<<10000, 256, 0, stream>>>(feat, 128, feat, 128, 1.f, 0.f, tx1, 128, packL, offs);
  k_prop<128><<<10000, 256, 0, stream>>>(tx1, 128, feat, 128, 2.f, -1.f, tx2, 128, packL, offs);
  k_prop<128><<<10000, 256, 0, stream>>>(tx2, 128, tx1, 128, 2.f, -1.f, tx3, 128, packL, offs);
  k_combine<128><<<2500, 512, 0, stream>>>(feat, 128, tx1, 128, tx2, 128, tx3, 128, cw[0], jk);
  // cheb layers 1..3 (input dim 64, read from jk slice)
  for (int l = 1; l < 4; ++l) {
    const float* xin = jk + (l - 1) * 64;
    k_prop<64><<<5000, 256, 0, stream>>>(xin, 256, xin, 256, 1.f, 0.f, tx1, 64, packL, offs);
    k_prop<64><<<5000, 256, 0, stream>>>(tx1, 64, xin, 256, 2.f, -1.f, tx2, 64, packL, offs);
    k_prop<64><<<5000, 256, 0, stream>>>(tx2, 64, tx1, 64, 2.f, -1.f, tx3, 64, packL, offs);
    k_combine<64><<<2500, 512, 0, stream>>>(xin, 256, tx1, 64, tx2, 64, tx3, 64, cw[l], jk + l * 64);
  }
  k_mlogit<<<1250, 256, 0, stream>>>(jk, Wm1t, bm1, Wm2, bm2, logit1);

  k_h0<<<1250, 256, 0, stream>>>(feat, Wl, bl, h0);
  const float* hprev = h0;
  for (int s = 0; s < 25; ++s) {
    float* hout = states + (size_t)s * NN * 16;
    k_bys<<<1250, 256, 0, stream>>>(hprev, noise + (size_t)s * NN * 16, hout, packW, offs);
    hprev = hout;
  }
  k_final<<<5000, 256, 0, stream>>>(states, Whl, bhl, logit1, outp);
}